// Round 18
// baseline (654.572 us; speedup 1.0000x reference)
//
#include <hip/hip_runtime.h>
#include <hip/hip_bf16.h>

typedef __bf16 bf16;
typedef __bf16 bf16x8 __attribute__((ext_vector_type(8)));
typedef __bf16 bf16x4 __attribute__((ext_vector_type(4)));
typedef float f32x4 __attribute__((ext_vector_type(4)));

#define NT 8192   // tokens = B*S
#define DD 1024   // model dim
#define HH 4096   // hidden dim
#define NE 8      // experts
#define TMAX 136  // max sum of ceil(count_e/128): 128 + 8 partial tiles

__device__ __forceinline__ void gload_lds16(const void* g, void* l) {
  __builtin_amdgcn_global_load_lds(
      (__attribute__((address_space(1))) void*)(g),
      (__attribute__((address_space(3))) void*)(l), 16, 0, 0);
}

// ---- merged W1+W2 transpose: [E][R][C] f32 -> [E][C][R] bf16 ----
// R18: 128rows x 64cols tiles; BOTH sides move 256B contiguous per 16-lane
// group (loads: 4 rows x 256B/wave; stores: 128-elem bf16 chunks = 256B).
// LDS pad +1: write-side 2-way (free), read-side 4-way (1.58x, not the bound).
__global__ __launch_bounds__(256) void k_transpose_both(
    const float* __restrict__ W1, const float* __restrict__ W2,
    bf16* __restrict__ W1T, bf16* __restrict__ W2T) {
  __shared__ float tile[128][65];
  const int z = blockIdx.z;
  const float* in;
  bf16* out;
  int R, C;
  if (z < 8) { in = W1 + (size_t)z * DD * HH; out = W1T + (size_t)z * DD * HH; R = DD; C = HH; }
  else       { in = W2 + (size_t)(z - 8) * DD * HH; out = W2T + (size_t)(z - 8) * DD * HH; R = HH; C = DD; }
  const int ntx = C >> 6;
  const int r0 = (blockIdx.x / ntx) << 7, c0 = (blockIdx.x % ntx) << 6;
  const int t = threadIdx.x;
  const int lrr = t >> 4, lc4 = (t & 15) * 4;
#pragma unroll
  for (int i = 0; i < 8; ++i) {
    int r = i * 16 + lrr;
    float4 v = *reinterpret_cast<const float4*>(in + (size_t)(r0 + r) * C + c0 + lc4);
    tile[r][lc4] = v.x; tile[r][lc4 + 1] = v.y; tile[r][lc4 + 2] = v.z; tile[r][lc4 + 3] = v.w;
  }
  __syncthreads();
  const int oc = t >> 4, m = t & 15;
#pragma unroll
  for (int cc = 0; cc < 4; ++cc) {
    int c = cc * 16 + oc;
    bf16x8 v;
#pragma unroll
    for (int k = 0; k < 8; ++k) v[k] = (bf16)tile[m * 8 + k][c];
    *reinterpret_cast<bf16x8*>(out + (size_t)(c0 + c) * R + r0 + m * 8) = v;
  }
}

// ---------------- router (+ fused x -> bf16 conversion) ----------------
__global__ __launch_bounds__(256) void k_router(
    const float* __restrict__ x, const float* __restrict__ Wr,
    bf16* __restrict__ xb,
    float* __restrict__ gate, int* __restrict__ lists, int* __restrict__ counts,
    float* __restrict__ auxpart) {
  __shared__ float bp[4][8];
  int wv = threadIdx.x >> 6, l = threadIdx.x & 63;
  int t = blockIdx.x * 4 + wv;
  const float* xr = x + (size_t)t * DD;
  bf16* xbr = xb + (size_t)t * DD;
  float p[8];
#pragma unroll
  for (int e = 0; e < 8; ++e) p[e] = 0.f;
#pragma unroll
  for (int c = 0; c < 4; ++c) {
    int d0 = c * 256 + l * 4;
    float4 xv = *reinterpret_cast<const float4*>(xr + d0);
    bf16x4 o;
    o[0] = (bf16)xv.x; o[1] = (bf16)xv.y; o[2] = (bf16)xv.z; o[3] = (bf16)xv.w;
    *reinterpret_cast<bf16x4*>(xbr + d0) = o;
    float xs[4] = {xv.x, xv.y, xv.z, xv.w};
#pragma unroll
    for (int j = 0; j < 4; ++j) {
      float4 w0 = *reinterpret_cast<const float4*>(Wr + (size_t)(d0 + j) * 8);
      float4 w1 = *reinterpret_cast<const float4*>(Wr + (size_t)(d0 + j) * 8 + 4);
      p[0] += xs[j] * w0.x; p[1] += xs[j] * w0.y;
      p[2] += xs[j] * w0.z; p[3] += xs[j] * w0.w;
      p[4] += xs[j] * w1.x; p[5] += xs[j] * w1.y;
      p[6] += xs[j] * w1.z; p[7] += xs[j] * w1.w;
    }
  }
#pragma unroll
  for (int off = 32; off >= 1; off >>= 1)
#pragma unroll
    for (int e = 0; e < 8; ++e) p[e] += __shfl_down(p[e], off);
  if (l == 0) {
    float m = p[0];
#pragma unroll
    for (int e = 1; e < 8; ++e) m = fmaxf(m, p[e]);
    float pr[8], s = 0.f;
#pragma unroll
    for (int e = 0; e < 8; ++e) { pr[e] = expf(p[e] - m); s += pr[e]; }
    float inv = 1.f / s;
#pragma unroll
    for (int e = 0; e < 8; ++e) pr[e] *= inv;
    int i1 = 0;
#pragma unroll
    for (int e = 1; e < 8; ++e) if (pr[e] > pr[i1]) i1 = e;
    int i2 = (i1 == 0) ? 1 : 0;
#pragma unroll
    for (int e = 0; e < 8; ++e) if (e != i1 && pr[e] > pr[i2]) i2 = e;
    float wsum = pr[i1] + pr[i2];
    gate[t * 8 + i1] = pr[i1] / wsum;
    gate[t * 8 + i2] = pr[i2] / wsum;
    int p1 = atomicAdd(&counts[i1], 1); lists[i1 * NT + p1] = t;
    int p2 = atomicAdd(&counts[i2], 1); lists[i2 * NT + p2] = t;
#pragma unroll
    for (int e = 0; e < 8; ++e) bp[wv][e] = pr[e];
  }
  __syncthreads();
  if (threadIdx.x < 8) {
    float s = bp[0][threadIdx.x] + bp[1][threadIdx.x] +
              bp[2][threadIdx.x] + bp[3][threadIdx.x];
    auxpart[blockIdx.x * 8 + threadIdx.x] = s;
  }
}

// --------- aux loss + prefix offsets + tile-prefix (for GEMM2 XCD coloring) ---------
__global__ void k_finalize(const int* __restrict__ counts, int* __restrict__ offs,
                           const float* __restrict__ auxpart, float* __restrict__ aux_out) {
  __shared__ float sh[32][8];
  int e = threadIdx.x & 7, chunk = threadIdx.x >> 3;  // 256 threads
  float s = 0.f;
  for (int b = chunk * 64; b < chunk * 64 + 64; ++b) s += auxpart[b * 8 + e];
  sh[chunk][e] = s;
  __syncthreads();
  if (threadIdx.x < 8) {
    float tot = 0.f;
    for (int c = 0; c < 32; ++c) tot += sh[c][threadIdx.x];
    float d = tot * (1.f / 8192.f) - 0.125f;
    sh[0][threadIdx.x] = d * d;
  }
  __syncthreads();
  if (threadIdx.x == 0) {
    float loss = 0.f;
    for (int e2 = 0; e2 < 8; ++e2) loss += sh[0][e2];
    aux_out[0] = loss;
    int o = 0, t = 0;
    for (int e2 = 0; e2 < 8; ++e2) {
      offs[e2] = o;       o += counts[e2];
      offs[16 + e2] = t;  t += (counts[e2] + 127) >> 7;   // tile prefix (tcum)
    }
    offs[8] = o;
    offs[24] = t;   // T = total (e,mt) pairs
  }
}

// ------ grouped expert GEMM (128x128, BK=64, LDS dbuf) — asymmetric grids ------
// GEMM1 (!COLORED): R14 2-D n-fast grid — B slab shared via 32MB AGGREGATE L2.
// GEMM2 (COLORED): R16 1-D XCD-colored grid — pair's A-tile pinned to one XCD L2.
// Core schedule frozen: R7 dbuf, vmcnt(8), tanh-GELU, swizzle c^(r&7).
#define BAR() do { asm volatile("" ::: "memory"); \
                   __builtin_amdgcn_s_barrier(); \
                   asm volatile("" ::: "memory"); } while (0)

template <int KTOT, int NTOT, bool IS_G1, bool COLORED>
__global__ __launch_bounds__(256, 2) void k_moe_gemm(
    const bf16* __restrict__ A, const bf16* __restrict__ Bw,
    bf16* __restrict__ Hout, float* __restrict__ Yout,
    const int* __restrict__ lists, const int* __restrict__ counts,
    const int* __restrict__ offs, const float* __restrict__ gate) {
  const int NX = NTOT / 128;
  int e, m0, n0;
  if (COLORED) {
    const int d = blockIdx.x;
    const int* tcum = offs + 16;
    const int T = tcum[8];
    const int p = ((d >> 3) / NX) * 8 + (d & 7);
    if (p >= T) return;
    e = 0;
    while (e < 7 && tcum[e + 1] <= p) ++e;
    m0 = (p - tcum[e]) * 128;
    n0 = ((d >> 3) % NX) * 128;
  } else {
    e = blockIdx.z;
    m0 = blockIdx.y * 128;
    n0 = blockIdx.x * 128;
  }
  const int count = counts[e];
  if (m0 >= count) return;
  const int tid = threadIdx.x;
  const int w = tid >> 6, l = tid & 63;

  __shared__ __align__(16) char lds[65536];  // buf b at b*32768: A [0,16K), B [16K,32K)

  const int hoff = offs[e];
  const int sr = l >> 3;
  const int scol = ((l & 7) ^ sr) << 3;  // elems (pre-swizzled source col)
  const bf16* aptr[4];
  const bf16* bptr[4];
#pragma unroll
  for (int i = 0; i < 4; ++i) {
    int r = (i * 4 + w) * 8 + sr;
    int mrow = m0 + r; if (mrow > count - 1) mrow = count - 1;
    size_t arow = IS_G1 ? (size_t)lists[e * NT + mrow] : (size_t)(hoff + mrow);
    aptr[i] = A + arow * KTOT + scol;
    bptr[i] = Bw + (size_t)e * NTOT * KTOT + (size_t)(n0 + r) * KTOT + scol;
  }

  f32x4 acc[4][4];
#pragma unroll
  for (int mi = 0; mi < 4; ++mi)
#pragma unroll
    for (int ni = 0; ni < 4; ++ni) acc[mi][ni] = (f32x4){0.f, 0.f, 0.f, 0.f};

  // stage k-tile 0 -> buf0
#pragma unroll
  for (int i = 0; i < 4; ++i) gload_lds16(aptr[i], &lds[(i * 4 + w) * 1024]);
#pragma unroll
  for (int i = 0; i < 4; ++i) gload_lds16(bptr[i], &lds[16384 + (i * 4 + w) * 1024]);

  const int wm = w >> 1, wn = w & 1;
  const int lr = l & 15, lk = l >> 4;
  const int cb = (lk * 16) ^ ((l & 7) << 4);  // swizzled byte col
  const int abase = (wm * 64 + lr) * 128 + cb;
  const int bbase = 16384 + (wn * 64 + lr) * 128 + cb;

  const int NKT = KTOT / 64;
#pragma unroll 1
  for (int kt = 0; kt < NKT; ++kt) {
    const int cur = (kt & 1) * 32768;
    if (kt + 1 < NKT) {
      const int nxt = cur ^ 32768;
      const size_t ko = (size_t)(kt + 1) * 64;
#pragma unroll
      for (int i = 0; i < 4; ++i)
        gload_lds16(aptr[i] + ko, &lds[nxt + (i * 4 + w) * 1024]);
#pragma unroll
      for (int i = 0; i < 4; ++i)
        gload_lds16(bptr[i] + ko, &lds[nxt + 16384 + (i * 4 + w) * 1024]);
      asm volatile("s_waitcnt vmcnt(8)" ::: "memory");  // tile kt landed; kt+1 in flight
    } else {
      asm volatile("s_waitcnt vmcnt(0)" ::: "memory");
    }
    BAR();
#pragma unroll
    for (int ks = 0; ks < 2; ++ks) {
      bf16x8 af[4], bfr[4];
#pragma unroll
      for (int mi = 0; mi < 4; ++mi)
        af[mi] = *reinterpret_cast<const bf16x8*>(&lds[cur + ((abase + mi * 2048) ^ (ks << 6))]);
#pragma unroll
      for (int ni = 0; ni < 4; ++ni)
        bfr[ni] = *reinterpret_cast<const bf16x8*>(&lds[cur + ((bbase + ni * 2048) ^ (ks << 6))]);
#pragma unroll
      for (int mi = 0; mi < 4; ++mi)
#pragma unroll
        for (int ni = 0; ni < 4; ++ni)
          acc[mi][ni] = __builtin_amdgcn_mfma_f32_16x16x32_bf16(
              af[mi], bfr[ni], acc[mi][ni], 0, 0, 0);
    }
    BAR();  // all waves done reading buf cur -> next iter may overwrite it
  }

  // epilogue: tanh-approx GELU for G1, gated atomic scatter for G2
#pragma unroll
  for (int mi = 0; mi < 4; ++mi) {
#pragma unroll
    for (int j = 0; j < 4; ++j) {
      int row = wm * 64 + mi * 16 + lk * 4 + j;
      int m = m0 + row;
      if (m < count) {
        if (IS_G1) {
          size_t base = (size_t)(hoff + m) * NTOT + n0 + wn * 64 + lr;
#pragma unroll
          for (int ni = 0; ni < 4; ++ni) {
            float v = acc[mi][ni][j];
            float u = v + 0.044715f * v * v * v;
            float g = v / (1.f + __expf(-1.5957691216057308f * u));
            Hout[base + ni * 16] = (bf16)g;
          }
        } else {
          int tok = lists[e * NT + m];
          float wg = gate[tok * 8 + e];
          size_t base = (size_t)tok * 1024 + n0 + wn * 64 + lr;
#pragma unroll
          for (int ni = 0; ni < 4; ++ni)
            unsafeAtomicAdd(&Yout[base + ni * 16], wg * acc[mi][ni][j]);
        }
      }
    }
  }
}

extern "C" void kernel_launch(void* const* d_in, const int* in_sizes, int n_in,
                              void* d_out, int out_size, void* d_ws, size_t ws_size,
                              hipStream_t stream) {
  const float* x = (const float*)d_in[0];
  const float* Wr = (const float*)d_in[1];
  const float* W1 = (const float*)d_in[2];
  const float* W2 = (const float*)d_in[3];
  float* out = (float*)d_out;

  char* ws = (char*)d_ws;
  size_t off = 0;
  bf16* Xb = (bf16*)(ws + off);  off += (size_t)NT * DD * 2;        // 16.8 MB
  bf16* W1T = (bf16*)(ws + off); off += (size_t)NE * DD * HH * 2;   // 67 MB
  bf16* W2T = (bf16*)(ws + off); off += (size_t)NE * DD * HH * 2;   // 67 MB
  bf16* Hb = (bf16*)(ws + off);  off += (size_t)NT * 2 * HH * 2;    // 134 MB (16384 rows)
  float* gate = (float*)(ws + off); off += (size_t)NT * 8 * 4;
  int* lists = (int*)(ws + off);    off += (size_t)NE * NT * 4;
  int* counts = (int*)(ws + off);   off += 64;
  int* offs = (int*)(ws + off);     off += 128;  // [0..8] row offs, [16..24] tile prefix
  float* auxpart = (float*)(ws + off); off += (size_t)(NT / 4) * 8 * 4;

  hipMemsetAsync(d_out, 0, (size_t)out_size * 4, stream);
  hipMemsetAsync(counts, 0, 64, stream);

  k_transpose_both<<<dim3((DD / 128) * (HH / 64), 1, 2 * NE), 256, 0, stream>>>(
      W1, W2, W1T, W2T);
  k_router<<<NT / 4, 256, 0, stream>>>(x, Wr, Xb, gate, lists, counts, auxpart);
  k_finalize<<<1, 256, 0, stream>>>(counts, offs, auxpart, out + (size_t)NT * DD);
  k_moe_gemm<DD, HH, true, false><<<dim3(HH / 128, 64, NE), 256, 0, stream>>>(
      Xb, W1T, Hb, nullptr, lists, counts, offs, gate);
  k_moe_gemm<HH, DD, false, true><<<TMAX * (DD / 128), 256, 0, stream>>>(
      Hb, W2T, nullptr, out, lists, counts, offs, gate);
}

// Round 19
// 653.868 us; speedup vs baseline: 1.0011x; 1.0011x over previous
//
#include <hip/hip_runtime.h>
#include <hip/hip_bf16.h>

typedef __bf16 bf16;
typedef __bf16 bf16x8 __attribute__((ext_vector_type(8)));
typedef __bf16 bf16x4 __attribute__((ext_vector_type(4)));
typedef float f32x4 __attribute__((ext_vector_type(4)));

#define NT 8192   // tokens = B*S
#define DD 1024   // model dim
#define HH 4096   // hidden dim
#define NE 8      // experts
#define TMAX 136  // max sum of ceil(count_e/128): 128 + 8 partial tiles

__device__ __forceinline__ void gload_lds16(const void* g, void* l) {
  __builtin_amdgcn_global_load_lds(
      (__attribute__((address_space(1))) void*)(g),
      (__attribute__((address_space(3))) void*)(l), 16, 0, 0);
}

// ---- merged W1+W2 transpose: [E][R][C] f32 -> [E][C][R] bf16 ----
__global__ __launch_bounds__(256) void k_transpose_both(
    const float* __restrict__ W1, const float* __restrict__ W2,
    bf16* __restrict__ W1T, bf16* __restrict__ W2T) {
  __shared__ float tile[128][65];
  const int z = blockIdx.z;
  const float* in;
  bf16* out;
  int R, C;
  if (z < 8) { in = W1 + (size_t)z * DD * HH; out = W1T + (size_t)z * DD * HH; R = DD; C = HH; }
  else       { in = W2 + (size_t)(z - 8) * DD * HH; out = W2T + (size_t)(z - 8) * DD * HH; R = HH; C = DD; }
  const int ntx = C >> 6;
  const int r0 = (blockIdx.x / ntx) << 7, c0 = (blockIdx.x % ntx) << 6;
  const int t = threadIdx.x;
  const int lrr = t >> 4, lc4 = (t & 15) * 4;
#pragma unroll
  for (int i = 0; i < 8; ++i) {
    int r = i * 16 + lrr;
    float4 v = *reinterpret_cast<const float4*>(in + (size_t)(r0 + r) * C + c0 + lc4);
    tile[r][lc4] = v.x; tile[r][lc4 + 1] = v.y; tile[r][lc4 + 2] = v.z; tile[r][lc4 + 3] = v.w;
  }
  __syncthreads();
  const int oc = t >> 4, m = t & 15;
#pragma unroll
  for (int cc = 0; cc < 4; ++cc) {
    int c = cc * 16 + oc;
    bf16x8 v;
#pragma unroll
    for (int k = 0; k < 8; ++k) v[k] = (bf16)tile[m * 8 + k][c];
    *reinterpret_cast<bf16x8*>(out + (size_t)(c0 + c) * R + r0 + m * 8) = v;
  }
}

// ---------------- router (+ fused x -> bf16 conversion) ----------------
__global__ __launch_bounds__(256) void k_router(
    const float* __restrict__ x, const float* __restrict__ Wr,
    bf16* __restrict__ xb,
    float* __restrict__ gate, int* __restrict__ lists, int* __restrict__ counts,
    float* __restrict__ auxpart) {
  __shared__ float bp[4][8];
  int wv = threadIdx.x >> 6, l = threadIdx.x & 63;
  int t = blockIdx.x * 4 + wv;
  const float* xr = x + (size_t)t * DD;
  bf16* xbr = xb + (size_t)t * DD;
  float p[8];
#pragma unroll
  for (int e = 0; e < 8; ++e) p[e] = 0.f;
#pragma unroll
  for (int c = 0; c < 4; ++c) {
    int d0 = c * 256 + l * 4;
    float4 xv = *reinterpret_cast<const float4*>(xr + d0);
    bf16x4 o;
    o[0] = (bf16)xv.x; o[1] = (bf16)xv.y; o[2] = (bf16)xv.z; o[3] = (bf16)xv.w;
    *reinterpret_cast<bf16x4*>(xbr + d0) = o;
    float xs[4] = {xv.x, xv.y, xv.z, xv.w};
#pragma unroll
    for (int j = 0; j < 4; ++j) {
      float4 w0 = *reinterpret_cast<const float4*>(Wr + (size_t)(d0 + j) * 8);
      float4 w1 = *reinterpret_cast<const float4*>(Wr + (size_t)(d0 + j) * 8 + 4);
      p[0] += xs[j] * w0.x; p[1] += xs[j] * w0.y;
      p[2] += xs[j] * w0.z; p[3] += xs[j] * w0.w;
      p[4] += xs[j] * w1.x; p[5] += xs[j] * w1.y;
      p[6] += xs[j] * w1.z; p[7] += xs[j] * w1.w;
    }
  }
#pragma unroll
  for (int off = 32; off >= 1; off >>= 1)
#pragma unroll
    for (int e = 0; e < 8; ++e) p[e] += __shfl_down(p[e], off);
  if (l == 0) {
    float m = p[0];
#pragma unroll
    for (int e = 1; e < 8; ++e) m = fmaxf(m, p[e]);
    float pr[8], s = 0.f;
#pragma unroll
    for (int e = 0; e < 8; ++e) { pr[e] = expf(p[e] - m); s += pr[e]; }
    float inv = 1.f / s;
#pragma unroll
    for (int e = 0; e < 8; ++e) pr[e] *= inv;
    int i1 = 0;
#pragma unroll
    for (int e = 1; e < 8; ++e) if (pr[e] > pr[i1]) i1 = e;
    int i2 = (i1 == 0) ? 1 : 0;
#pragma unroll
    for (int e = 0; e < 8; ++e) if (e != i1 && pr[e] > pr[i2]) i2 = e;
    float wsum = pr[i1] + pr[i2];
    gate[t * 8 + i1] = pr[i1] / wsum;
    gate[t * 8 + i2] = pr[i2] / wsum;
    int p1 = atomicAdd(&counts[i1], 1); lists[i1 * NT + p1] = t;
    int p2 = atomicAdd(&counts[i2], 1); lists[i2 * NT + p2] = t;
#pragma unroll
    for (int e = 0; e < 8; ++e) bp[wv][e] = pr[e];
  }
  __syncthreads();
  if (threadIdx.x < 8) {
    float s = bp[0][threadIdx.x] + bp[1][threadIdx.x] +
              bp[2][threadIdx.x] + bp[3][threadIdx.x];
    auxpart[blockIdx.x * 8 + threadIdx.x] = s;
  }
}

// --------- aux loss + prefix offsets + tile-prefix (for GEMM2 XCD coloring) ---------
__global__ void k_finalize(const int* __restrict__ counts, int* __restrict__ offs,
                           const float* __restrict__ auxpart, float* __restrict__ aux_out) {
  __shared__ float sh[32][8];
  int e = threadIdx.x & 7, chunk = threadIdx.x >> 3;  // 256 threads
  float s = 0.f;
  for (int b = chunk * 64; b < chunk * 64 + 64; ++b) s += auxpart[b * 8 + e];
  sh[chunk][e] = s;
  __syncthreads();
  if (threadIdx.x < 8) {
    float tot = 0.f;
    for (int c = 0; c < 32; ++c) tot += sh[c][threadIdx.x];
    float d = tot * (1.f / 8192.f) - 0.125f;
    sh[0][threadIdx.x] = d * d;
  }
  __syncthreads();
  if (threadIdx.x == 0) {
    float loss = 0.f;
    for (int e2 = 0; e2 < 8; ++e2) loss += sh[0][e2];
    aux_out[0] = loss;
    int o = 0, t = 0;
    for (int e2 = 0; e2 < 8; ++e2) {
      offs[e2] = o;       o += counts[e2];
      offs[16 + e2] = t;  t += (counts[e2] + 127) >> 7;   // tile prefix (tcum)
    }
    offs[8] = o;
    offs[24] = t;   // T = total (e,mt) pairs
  }
}

// --- grouped expert GEMM (128x128, BK=64, LDS dbuf) — 512 threads / 8 waves ---
// R19: same tile, same R7 schedule, same grids — but 8 waves/block (2M x 4N,
// per-wave 64x32 output). 2 blocks/CU -> 16 waves/CU (4/SIMD), doubling the
// latency-hiding pool in the diagnosed latency/sync-bound regime.
// Staging: 4 gloads/thread (2 A + 2 B), vmcnt(4) gate, wave-uniform LDS bases
// (wave w covers rows w*8+..), swizzle c^(r&7) both sides (0 conflicts).
// GEMM1 (!COLORED): 2-D n-fast grid (aggregate-L2 B sharing).
// GEMM2 (COLORED): 1-D XCD-colored grid (pair's A-tile pinned to one XCD L2).
#define BAR() do { asm volatile("" ::: "memory"); \
                   __builtin_amdgcn_s_barrier(); \
                   asm volatile("" ::: "memory"); } while (0)

template <int KTOT, int NTOT, bool IS_G1, bool COLORED>
__global__ __launch_bounds__(512, 4) void k_moe_gemm(
    const bf16* __restrict__ A, const bf16* __restrict__ Bw,
    bf16* __restrict__ Hout, float* __restrict__ Yout,
    const int* __restrict__ lists, const int* __restrict__ counts,
    const int* __restrict__ offs, const float* __restrict__ gate) {
  const int NX = NTOT / 128;
  int e, m0, n0;
  if (COLORED) {
    const int d = blockIdx.x;
    const int* tcum = offs + 16;
    const int T = tcum[8];
    const int p = ((d >> 3) / NX) * 8 + (d & 7);
    if (p >= T) return;
    e = 0;
    while (e < 7 && tcum[e + 1] <= p) ++e;
    m0 = (p - tcum[e]) * 128;
    n0 = ((d >> 3) % NX) * 128;
  } else {
    e = blockIdx.z;
    m0 = blockIdx.y * 128;
    n0 = blockIdx.x * 128;
  }
  const int count = counts[e];
  if (m0 >= count) return;
  const int tid = threadIdx.x;
  const int w = tid >> 6, l = tid & 63;

  __shared__ __align__(16) char lds[65536];  // buf b at b*32768: A [0,16K), B [16K,32K)

  const int hoff = offs[e];
  // staging: thread covers rows r = i*64 + (tid>>3) (i=0,1), chunk (tid&7);
  // source col pre-swizzled with the read-side involution (rule #21).
  const int srow = tid >> 3;               // 0..63
  const int schunk = ((tid & 7) ^ (srow & 7)) << 3;  // elems
  const bf16* aptr[2];
  const bf16* bptr[2];
#pragma unroll
  for (int i = 0; i < 2; ++i) {
    int r = i * 64 + srow;
    int mrow = m0 + r; if (mrow > count - 1) mrow = count - 1;
    size_t arow = IS_G1 ? (size_t)lists[e * NT + mrow] : (size_t)(hoff + mrow);
    aptr[i] = A + arow * KTOT + schunk;
    bptr[i] = Bw + (size_t)e * NTOT * KTOT + (size_t)(n0 + r) * KTOT + schunk;
  }
  // LDS dest base (wave-uniform + lane*16): wave w, half i -> i*8192 + w*1024
  f32x4 acc[4][2];
#pragma unroll
  for (int mi = 0; mi < 4; ++mi)
#pragma unroll
    for (int ni = 0; ni < 2; ++ni) acc[mi][ni] = (f32x4){0.f, 0.f, 0.f, 0.f};

  // stage k-tile 0 -> buf0
#pragma unroll
  for (int i = 0; i < 2; ++i) gload_lds16(aptr[i], &lds[i * 8192 + w * 1024]);
#pragma unroll
  for (int i = 0; i < 2; ++i) gload_lds16(bptr[i], &lds[16384 + i * 8192 + w * 1024]);

  const int wm = w >> 2, wn = w & 3;       // 2M x 4N wave decomp
  const int lr = l & 15, lk = l >> 4;
  const int cb = (lk * 16) ^ ((l & 7) << 4);  // swizzled byte col
  const int abase = (wm * 64 + lr) * 128 + cb;
  const int bbase = 16384 + (wn * 32 + lr) * 128 + cb;

  const int NKT = KTOT / 64;
#pragma unroll 1
  for (int kt = 0; kt < NKT; ++kt) {
    const int cur = (kt & 1) * 32768;
    if (kt + 1 < NKT) {
      const int nxt = cur ^ 32768;
      const size_t ko = (size_t)(kt + 1) * 64;
#pragma unroll
      for (int i = 0; i < 2; ++i)
        gload_lds16(aptr[i] + ko, &lds[nxt + i * 8192 + w * 1024]);
#pragma unroll
      for (int i = 0; i < 2; ++i)
        gload_lds16(bptr[i] + ko, &lds[nxt + 16384 + i * 8192 + w * 1024]);
      asm volatile("s_waitcnt vmcnt(4)" ::: "memory");  // tile kt landed; kt+1 in flight
    } else {
      asm volatile("s_waitcnt vmcnt(0)" ::: "memory");
    }
    BAR();
#pragma unroll
    for (int ks = 0; ks < 2; ++ks) {
      bf16x8 af[4], bfr[2];
#pragma unroll
      for (int mi = 0; mi < 4; ++mi)
        af[mi] = *reinterpret_cast<const bf16x8*>(&lds[cur + ((abase + mi * 2048) ^ (ks << 6))]);
#pragma unroll
      for (int ni = 0; ni < 2; ++ni)
        bfr[ni] = *reinterpret_cast<const bf16x8*>(&lds[cur + ((bbase + ni * 2048) ^ (ks << 6))]);
#pragma unroll
      for (int mi = 0; mi < 4; ++mi)
#pragma unroll
        for (int ni = 0; ni < 2; ++ni)
          acc[mi][ni] = __builtin_amdgcn_mfma_f32_16x16x32_bf16(
              af[mi], bfr[ni], acc[mi][ni], 0, 0, 0);
    }
    BAR();  // all waves done reading buf cur -> next iter may overwrite it
  }

  // epilogue: rows wm*64+mi*16+lk*4+j, cols n0+wn*32+ni*16+lr
#pragma unroll
  for (int mi = 0; mi < 4; ++mi) {
#pragma unroll
    for (int j = 0; j < 4; ++j) {
      int row = wm * 64 + mi * 16 + lk * 4 + j;
      int m = m0 + row;
      if (m < count) {
        if (IS_G1) {
          size_t base = (size_t)(hoff + m) * NTOT + n0 + wn * 32 + lr;
#pragma unroll
          for (int ni = 0; ni < 2; ++ni) {
            float v = acc[mi][ni][j];
            float u = v + 0.044715f * v * v * v;
            float g = v / (1.f + __expf(-1.5957691216057308f * u));
            Hout[base + ni * 16] = (bf16)g;
          }
        } else {
          int tok = lists[e * NT + m];
          float wg = gate[tok * 8 + e];
          size_t base = (size_t)tok * 1024 + n0 + wn * 32 + lr;
#pragma unroll
          for (int ni = 0; ni < 2; ++ni)
            unsafeAtomicAdd(&Yout[base + ni * 16], wg * acc[mi][ni][j]);
        }
      }
    }
  }
}

extern "C" void kernel_launch(void* const* d_in, const int* in_sizes, int n_in,
                              void* d_out, int out_size, void* d_ws, size_t ws_size,
                              hipStream_t stream) {
  const float* x = (const float*)d_in[0];
  const float* Wr = (const float*)d_in[1];
  const float* W1 = (const float*)d_in[2];
  const float* W2 = (const float*)d_in[3];
  float* out = (float*)d_out;

  char* ws = (char*)d_ws;
  size_t off = 0;
  bf16* Xb = (bf16*)(ws + off);  off += (size_t)NT * DD * 2;        // 16.8 MB
  bf16* W1T = (bf16*)(ws + off); off += (size_t)NE * DD * HH * 2;   // 67 MB
  bf16* W2T = (bf16*)(ws + off); off += (size_t)NE * DD * HH * 2;   // 67 MB
  bf16* Hb = (bf16*)(ws + off);  off += (size_t)NT * 2 * HH * 2;    // 134 MB (16384 rows)
  float* gate = (float*)(ws + off); off += (size_t)NT * 8 * 4;
  int* lists = (int*)(ws + off);    off += (size_t)NE * NT * 4;
  int* counts = (int*)(ws + off);   off += 64;
  int* offs = (int*)(ws + off);     off += 128;  // [0..8] row offs, [16..24] tile prefix
  float* auxpart = (float*)(ws + off); off += (size_t)(NT / 4) * 8 * 4;

  hipMemsetAsync(d_out, 0, (size_t)out_size * 4, stream);
  hipMemsetAsync(counts, 0, 64, stream);

  k_transpose_both<<<dim3((DD / 128) * (HH / 64), 1, 2 * NE), 256, 0, stream>>>(
      W1, W2, W1T, W2T);
  k_router<<<NT / 4, 256, 0, stream>>>(x, Wr, Xb, gate, lists, counts, auxpart);
  k_finalize<<<1, 256, 0, stream>>>(counts, offs, auxpart, out + (size_t)NT * DD);
  k_moe_gemm<DD, HH, true, false><<<dim3(HH / 128, 64, NE), 512, 0, stream>>>(
      Xb, W1T, Hb, nullptr, lists, counts, offs, gate);
  k_moe_gemm<HH, DD, false, true><<<TMAX * (DD / 128), 512, 0, stream>>>(
      Hb, W2T, nullptr, out, lists, counts, offs, gate);
}

// Round 20
// 486.952 us; speedup vs baseline: 1.3442x; 1.3428x over previous
//
#include <hip/hip_runtime.h>
#include <hip/hip_bf16.h>

typedef __bf16 bf16;
typedef __bf16 bf16x8 __attribute__((ext_vector_type(8)));
typedef __bf16 bf16x4 __attribute__((ext_vector_type(4)));
typedef float f32x4 __attribute__((ext_vector_type(4)));

#define NT 8192   // tokens = B*S
#define DD 1024   // model dim
#define HH 4096   // hidden dim
#define NE 8      // experts
#define TMAX 136  // max sum of ceil(count_e/128): 128 + 8 partial tiles

__device__ __forceinline__ void gload_lds16(const void* g, void* l) {
  __builtin_amdgcn_global_load_lds(
      (__attribute__((address_space(1))) void*)(g),
      (__attribute__((address_space(3))) void*)(l), 16, 0, 0);
}

// ---- merged W1+W2 transpose: [E][R][C] f32 -> [E][C][R] bf16 ----
__global__ __launch_bounds__(256) void k_transpose_both(
    const float* __restrict__ W1, const float* __restrict__ W2,
    bf16* __restrict__ W1T, bf16* __restrict__ W2T) {
  __shared__ float tile[128][65];
  const int z = blockIdx.z;
  const float* in;
  bf16* out;
  int R, C;
  if (z < 8) { in = W1 + (size_t)z * DD * HH; out = W1T + (size_t)z * DD * HH; R = DD; C = HH; }
  else       { in = W2 + (size_t)(z - 8) * DD * HH; out = W2T + (size_t)(z - 8) * DD * HH; R = HH; C = DD; }
  const int ntx = C >> 6;
  const int r0 = (blockIdx.x / ntx) << 7, c0 = (blockIdx.x % ntx) << 6;
  const int t = threadIdx.x;
  const int lrr = t >> 4, lc4 = (t & 15) * 4;
#pragma unroll
  for (int i = 0; i < 8; ++i) {
    int r = i * 16 + lrr;
    float4 v = *reinterpret_cast<const float4*>(in + (size_t)(r0 + r) * C + c0 + lc4);
    tile[r][lc4] = v.x; tile[r][lc4 + 1] = v.y; tile[r][lc4 + 2] = v.z; tile[r][lc4 + 3] = v.w;
  }
  __syncthreads();
  const int oc = t >> 4, m = t & 15;
#pragma unroll
  for (int cc = 0; cc < 4; ++cc) {
    int c = cc * 16 + oc;
    bf16x8 v;
#pragma unroll
    for (int k = 0; k < 8; ++k) v[k] = (bf16)tile[m * 8 + k][c];
    *reinterpret_cast<bf16x8*>(out + (size_t)(c0 + c) * R + r0 + m * 8) = v;
  }
}

// -------- router: 32 tokens/block, LDS-aggregated atomics (R20) --------
// Old router: 2 return-value atomicAdds per token onto ONE cacheline of 8
// counters = 16384 globally-serialized atomics ~= 200us (measured: all pipes
// idle, occ 50%). Now: per-block LDS histogram + local ranks, ONE atomic per
// (block,expert), counters padded to separate cachelines (counts[e<<5]).
__global__ __launch_bounds__(256) void k_router(
    const float* __restrict__ x, const float* __restrict__ Wr,
    bf16* __restrict__ xb,
    float* __restrict__ gate, int* __restrict__ lists, int* __restrict__ counts,
    float* __restrict__ auxpart) {
  __shared__ float sw[4][8];
  __shared__ unsigned char sei[32][2];
  __shared__ unsigned char spos[32][2];
  __shared__ int sbase[8];
  const int wv = threadIdx.x >> 6, l = threadIdx.x & 63;
  const int t0 = blockIdx.x * 32;
  float paux[8];
#pragma unroll
  for (int e = 0; e < 8; ++e) paux[e] = 0.f;

#pragma unroll 1
  for (int tt = 0; tt < 8; ++tt) {
    const int t = t0 + wv * 8 + tt;
    const float* xr = x + (size_t)t * DD;
    bf16* xbr = xb + (size_t)t * DD;
    float p[8];
#pragma unroll
    for (int e = 0; e < 8; ++e) p[e] = 0.f;
#pragma unroll
    for (int c = 0; c < 4; ++c) {
      int d0 = c * 256 + l * 4;
      float4 xv = *reinterpret_cast<const float4*>(xr + d0);
      bf16x4 o;
      o[0] = (bf16)xv.x; o[1] = (bf16)xv.y; o[2] = (bf16)xv.z; o[3] = (bf16)xv.w;
      *reinterpret_cast<bf16x4*>(xbr + d0) = o;
      float xs[4] = {xv.x, xv.y, xv.z, xv.w};
#pragma unroll
      for (int j = 0; j < 4; ++j) {
        float4 w0 = *reinterpret_cast<const float4*>(Wr + (size_t)(d0 + j) * 8);
        float4 w1 = *reinterpret_cast<const float4*>(Wr + (size_t)(d0 + j) * 8 + 4);
        p[0] += xs[j] * w0.x; p[1] += xs[j] * w0.y;
        p[2] += xs[j] * w0.z; p[3] += xs[j] * w0.w;
        p[4] += xs[j] * w1.x; p[5] += xs[j] * w1.y;
        p[6] += xs[j] * w1.z; p[7] += xs[j] * w1.w;
      }
    }
#pragma unroll
    for (int off = 32; off >= 1; off >>= 1)
#pragma unroll
      for (int e = 0; e < 8; ++e) p[e] += __shfl_down(p[e], off);
    if (l == 0) {
      float m = p[0];
#pragma unroll
      for (int e = 1; e < 8; ++e) m = fmaxf(m, p[e]);
      float pr[8], s = 0.f;
#pragma unroll
      for (int e = 0; e < 8; ++e) { pr[e] = expf(p[e] - m); s += pr[e]; }
      float inv = 1.f / s;
#pragma unroll
      for (int e = 0; e < 8; ++e) { pr[e] *= inv; paux[e] += pr[e]; }
      int i1 = 0;
#pragma unroll
      for (int e = 1; e < 8; ++e) if (pr[e] > pr[i1]) i1 = e;
      int i2 = (i1 == 0) ? 1 : 0;
#pragma unroll
      for (int e = 0; e < 8; ++e) if (e != i1 && pr[e] > pr[i2]) i2 = e;
      float wsum = pr[i1] + pr[i2];
      gate[t * 8 + i1] = pr[i1] / wsum;
      gate[t * 8 + i2] = pr[i2] / wsum;
      int li = wv * 8 + tt;
      sei[li][0] = (unsigned char)i1;
      sei[li][1] = (unsigned char)i2;
    }
  }
  if (l == 0) {
#pragma unroll
    for (int e = 0; e < 8; ++e) sw[wv][e] = paux[e];
  }
  __syncthreads();
  if (threadIdx.x < 8) {
    const int e = threadIdx.x;
    auxpart[blockIdx.x * 8 + e] = sw[0][e] + sw[1][e] + sw[2][e] + sw[3][e];
    int cnt = 0;
#pragma unroll 1
    for (int i = 0; i < 32; ++i) {
      if (sei[i][0] == e) spos[i][0] = (unsigned char)cnt++;
      if (sei[i][1] == e) spos[i][1] = (unsigned char)cnt++;
    }
    if (cnt) sbase[e] = atomicAdd(&counts[e << 5], cnt);
  }
  __syncthreads();
  if (threadIdx.x < 64) {
    int i = threadIdx.x >> 1, k = threadIdx.x & 1;
    int e = sei[i][k];
    lists[e * NT + sbase[e] + spos[i][k]] = t0 + i;
  }
}

// --------- aux loss + prefix offsets + tile-prefix (for GEMM2 XCD coloring) ---------
__global__ void k_finalize(const int* __restrict__ counts, int* __restrict__ offs,
                           const float* __restrict__ auxpart, float* __restrict__ aux_out) {
  __shared__ float sh[32][8];
  int e = threadIdx.x & 7, chunk = threadIdx.x >> 3;  // 256 threads
  float s = 0.f;
  for (int b = chunk * 8; b < chunk * 8 + 8; ++b) s += auxpart[b * 8 + e];  // 256 blocks
  sh[chunk][e] = s;
  __syncthreads();
  if (threadIdx.x < 8) {
    float tot = 0.f;
    for (int c = 0; c < 32; ++c) tot += sh[c][threadIdx.x];
    float d = tot * (1.f / 8192.f) - 0.125f;
    sh[0][threadIdx.x] = d * d;
  }
  __syncthreads();
  if (threadIdx.x == 0) {
    float loss = 0.f;
    for (int e2 = 0; e2 < 8; ++e2) loss += sh[0][e2];
    aux_out[0] = loss;
    int o = 0, t = 0;
    for (int e2 = 0; e2 < 8; ++e2) {
      int c = counts[e2 << 5];
      offs[e2] = o;       o += c;
      offs[16 + e2] = t;  t += (c + 127) >> 7;   // tile prefix (tcum)
    }
    offs[8] = o;
    offs[24] = t;   // T = total (e,mt) pairs
  }
}

// --- grouped expert GEMM (128x128, BK=64, LDS dbuf) — 512 threads / 8 waves ---
// R19 config (kept): 8 waves/block (2M x 4N), 2 blocks/CU -> 16 waves/CU.
// R7 schedule: stage tile k+1 at top of iter k into buf^1, vmcnt(4) waits
// only tile k. Swizzle c^(r&7) both sides. tanh-approx GELU.
// GEMM1 (!COLORED): 2-D n-fast grid (aggregate-L2 B sharing).
// GEMM2 (COLORED): 1-D XCD-colored grid (pair's A-tile pinned to one XCD L2).
#define BAR() do { asm volatile("" ::: "memory"); \
                   __builtin_amdgcn_s_barrier(); \
                   asm volatile("" ::: "memory"); } while (0)

template <int KTOT, int NTOT, bool IS_G1, bool COLORED>
__global__ __launch_bounds__(512, 4) void k_moe_gemm(
    const bf16* __restrict__ A, const bf16* __restrict__ Bw,
    bf16* __restrict__ Hout, float* __restrict__ Yout,
    const int* __restrict__ lists, const int* __restrict__ counts,
    const int* __restrict__ offs, const float* __restrict__ gate) {
  const int NX = NTOT / 128;
  int e, m0, n0;
  if (COLORED) {
    const int d = blockIdx.x;
    const int* tcum = offs + 16;
    const int T = tcum[8];
    const int p = ((d >> 3) / NX) * 8 + (d & 7);
    if (p >= T) return;
    e = 0;
    while (e < 7 && tcum[e + 1] <= p) ++e;
    m0 = (p - tcum[e]) * 128;
    n0 = ((d >> 3) % NX) * 128;
  } else {
    e = blockIdx.z;
    m0 = blockIdx.y * 128;
    n0 = blockIdx.x * 128;
  }
  const int count = counts[e << 5];
  if (m0 >= count) return;
  const int tid = threadIdx.x;
  const int w = tid >> 6, l = tid & 63;

  __shared__ __align__(16) char lds[65536];  // buf b at b*32768: A [0,16K), B [16K,32K)

  const int hoff = offs[e];
  const int srow = tid >> 3;               // 0..63
  const int schunk = ((tid & 7) ^ (srow & 7)) << 3;  // elems (pre-swizzled)
  const bf16* aptr[2];
  const bf16* bptr[2];
#pragma unroll
  for (int i = 0; i < 2; ++i) {
    int r = i * 64 + srow;
    int mrow = m0 + r; if (mrow > count - 1) mrow = count - 1;
    size_t arow = IS_G1 ? (size_t)lists[e * NT + mrow] : (size_t)(hoff + mrow);
    aptr[i] = A + arow * KTOT + schunk;
    bptr[i] = Bw + (size_t)e * NTOT * KTOT + (size_t)(n0 + r) * KTOT + schunk;
  }
  f32x4 acc[4][2];
#pragma unroll
  for (int mi = 0; mi < 4; ++mi)
#pragma unroll
    for (int ni = 0; ni < 2; ++ni) acc[mi][ni] = (f32x4){0.f, 0.f, 0.f, 0.f};

  // stage k-tile 0 -> buf0
#pragma unroll
  for (int i = 0; i < 2; ++i) gload_lds16(aptr[i], &lds[i * 8192 + w * 1024]);
#pragma unroll
  for (int i = 0; i < 2; ++i) gload_lds16(bptr[i], &lds[16384 + i * 8192 + w * 1024]);

  const int wm = w >> 2, wn = w & 3;       // 2M x 4N wave decomp
  const int lr = l & 15, lk = l >> 4;
  const int cb = (lk * 16) ^ ((l & 7) << 4);  // swizzled byte col
  const int abase = (wm * 64 + lr) * 128 + cb;
  const int bbase = 16384 + (wn * 32 + lr) * 128 + cb;

  const int NKT = KTOT / 64;
#pragma unroll 1
  for (int kt = 0; kt < NKT; ++kt) {
    const int cur = (kt & 1) * 32768;
    if (kt + 1 < NKT) {
      const int nxt = cur ^ 32768;
      const size_t ko = (size_t)(kt + 1) * 64;
#pragma unroll
      for (int i = 0; i < 2; ++i)
        gload_lds16(aptr[i] + ko, &lds[nxt + i * 8192 + w * 1024]);
#pragma unroll
      for (int i = 0; i < 2; ++i)
        gload_lds16(bptr[i] + ko, &lds[nxt + 16384 + i * 8192 + w * 1024]);
      asm volatile("s_waitcnt vmcnt(4)" ::: "memory");  // tile kt landed; kt+1 in flight
    } else {
      asm volatile("s_waitcnt vmcnt(0)" ::: "memory");
    }
    BAR();
#pragma unroll
    for (int ks = 0; ks < 2; ++ks) {
      bf16x8 af[4], bfr[2];
#pragma unroll
      for (int mi = 0; mi < 4; ++mi)
        af[mi] = *reinterpret_cast<const bf16x8*>(&lds[cur + ((abase + mi * 2048) ^ (ks << 6))]);
#pragma unroll
      for (int ni = 0; ni < 2; ++ni)
        bfr[ni] = *reinterpret_cast<const bf16x8*>(&lds[cur + ((bbase + ni * 2048) ^ (ks << 6))]);
#pragma unroll
      for (int mi = 0; mi < 4; ++mi)
#pragma unroll
        for (int ni = 0; ni < 2; ++ni)
          acc[mi][ni] = __builtin_amdgcn_mfma_f32_16x16x32_bf16(
              af[mi], bfr[ni], acc[mi][ni], 0, 0, 0);
    }
    BAR();  // all waves done reading buf cur -> next iter may overwrite it
  }

  // epilogue: rows wm*64+mi*16+lk*4+j, cols n0+wn*32+ni*16+lr
#pragma unroll
  for (int mi = 0; mi < 4; ++mi) {
#pragma unroll
    for (int j = 0; j < 4; ++j) {
      int row = wm * 64 + mi * 16 + lk * 4 + j;
      int m = m0 + row;
      if (m < count) {
        if (IS_G1) {
          size_t base = (size_t)(hoff + m) * NTOT + n0 + wn * 32 + lr;
#pragma unroll
          for (int ni = 0; ni < 2; ++ni) {
            float v = acc[mi][ni][j];
            float u = v + 0.044715f * v * v * v;
            float g = v / (1.f + __expf(-1.5957691216057308f * u));
            Hout[base + ni * 16] = (bf16)g;
          }
        } else {
          int tok = lists[e * NT + m];
          float wg = gate[tok * 8 + e];
          size_t base = (size_t)tok * 1024 + n0 + wn * 32 + lr;
#pragma unroll
          for (int ni = 0; ni < 2; ++ni)
            unsafeAtomicAdd(&Yout[base + ni * 16], wg * acc[mi][ni][j]);
        }
      }
    }
  }
}

extern "C" void kernel_launch(void* const* d_in, const int* in_sizes, int n_in,
                              void* d_out, int out_size, void* d_ws, size_t ws_size,
                              hipStream_t stream) {
  const float* x = (const float*)d_in[0];
  const float* Wr = (const float*)d_in[1];
  const float* W1 = (const float*)d_in[2];
  const float* W2 = (const float*)d_in[3];
  float* out = (float*)d_out;

  char* ws = (char*)d_ws;
  size_t off = 0;
  bf16* Xb = (bf16*)(ws + off);  off += (size_t)NT * DD * 2;        // 16.8 MB
  bf16* W1T = (bf16*)(ws + off); off += (size_t)NE * DD * HH * 2;   // 67 MB
  bf16* W2T = (bf16*)(ws + off); off += (size_t)NE * DD * HH * 2;   // 67 MB
  bf16* Hb = (bf16*)(ws + off);  off += (size_t)NT * 2 * HH * 2;    // 134 MB (16384 rows)
  float* gate = (float*)(ws + off); off += (size_t)NT * 8 * 4;
  int* lists = (int*)(ws + off);    off += (size_t)NE * NT * 4;
  int* counts = (int*)(ws + off);   off += 1024;  // padded: counts[e<<5]
  int* offs = (int*)(ws + off);     off += 128;   // [0..8] row offs, [16..24] tile prefix
  float* auxpart = (float*)(ws + off); off += (size_t)256 * 8 * 4;

  hipMemsetAsync(d_out, 0, (size_t)out_size * 4, stream);
  hipMemsetAsync(counts, 0, 1024, stream);

  k_transpose_both<<<dim3((DD / 128) * (HH / 64), 1, 2 * NE), 256, 0, stream>>>(
      W1, W2, W1T, W2T);
  k_router<<<NT / 32, 256, 0, stream>>>(x, Wr, Xb, gate, lists, counts, auxpart);
  k_finalize<<<1, 256, 0, stream>>>(counts, offs, auxpart, out + (size_t)NT * DD);
  k_moe_gemm<DD, HH, true, false><<<dim3(HH / 128, 64, NE), 512, 0, stream>>>(
      Xb, W1T, Hb, nullptr, lists, counts, offs, gate);
  k_moe_gemm<HH, DD, false, true><<<TMAX * (DD / 128), 512, 0, stream>>>(
      Hb, W2T, nullptr, out, lists, counts, offs, gate);
}

// Round 21
// 474.416 us; speedup vs baseline: 1.3797x; 1.0264x over previous
//
#include <hip/hip_runtime.h>
#include <hip/hip_bf16.h>

typedef __bf16 bf16;
typedef __bf16 bf16x8 __attribute__((ext_vector_type(8)));
typedef __bf16 bf16x4 __attribute__((ext_vector_type(4)));
typedef float f32x4 __attribute__((ext_vector_type(4)));

#define NT 8192   // tokens = B*S
#define DD 1024   // model dim
#define HH 4096   // hidden dim
#define NE 8      // experts
#define TMAX 136  // max sum of ceil(count_e/128): 128 + 8 partial tiles

__device__ __forceinline__ void gload_lds16(const void* g, void* l) {
  __builtin_amdgcn_global_load_lds(
      (__attribute__((address_space(1))) void*)(g),
      (__attribute__((address_space(3))) void*)(l), 16, 0, 0);
}

// ---- merged preprocessing: router (gid<256) + W1/W2 transpose (gid>=256) ----
// Router and transposes are data-independent; one dispatch lets the 256 router
// blocks run concurrently under the 8192 transpose blocks (saves serialization
// + one launch). Router: 32 tokens/block, LDS-aggregated counts (1 atomic per
// block-expert, counters on separate cachelines). Transpose: 128x64 tiles,
// 256B-contiguous on both sides.
__global__ __launch_bounds__(256) void k_pre(
    const float* __restrict__ x, const float* __restrict__ Wr,
    bf16* __restrict__ xb, float* __restrict__ gate, int* __restrict__ lists,
    int* __restrict__ counts, float* __restrict__ auxpart,
    const float* __restrict__ W1, const float* __restrict__ W2,
    bf16* __restrict__ W1T, bf16* __restrict__ W2T) {
  __shared__ float tile[128][65];
  __shared__ float sw[4][8];
  __shared__ unsigned char sei[32][2];
  __shared__ unsigned char spos[32][2];
  __shared__ int sbase[8];

  const int gid = blockIdx.x;
  if (gid < 256) {
    // ------------------- router -------------------
    const int wv = threadIdx.x >> 6, l = threadIdx.x & 63;
    const int t0 = gid * 32;
    float paux[8];
#pragma unroll
    for (int e = 0; e < 8; ++e) paux[e] = 0.f;
#pragma unroll 1
    for (int tt = 0; tt < 8; ++tt) {
      const int t = t0 + wv * 8 + tt;
      const float* xr = x + (size_t)t * DD;
      bf16* xbr = xb + (size_t)t * DD;
      float p[8];
#pragma unroll
      for (int e = 0; e < 8; ++e) p[e] = 0.f;
#pragma unroll
      for (int c = 0; c < 4; ++c) {
        int d0 = c * 256 + l * 4;
        float4 xv = *reinterpret_cast<const float4*>(xr + d0);
        bf16x4 o;
        o[0] = (bf16)xv.x; o[1] = (bf16)xv.y; o[2] = (bf16)xv.z; o[3] = (bf16)xv.w;
        *reinterpret_cast<bf16x4*>(xbr + d0) = o;
        float xs[4] = {xv.x, xv.y, xv.z, xv.w};
#pragma unroll
        for (int j = 0; j < 4; ++j) {
          float4 w0 = *reinterpret_cast<const float4*>(Wr + (size_t)(d0 + j) * 8);
          float4 w1 = *reinterpret_cast<const float4*>(Wr + (size_t)(d0 + j) * 8 + 4);
          p[0] += xs[j] * w0.x; p[1] += xs[j] * w0.y;
          p[2] += xs[j] * w0.z; p[3] += xs[j] * w0.w;
          p[4] += xs[j] * w1.x; p[5] += xs[j] * w1.y;
          p[6] += xs[j] * w1.z; p[7] += xs[j] * w1.w;
        }
      }
#pragma unroll
      for (int off = 32; off >= 1; off >>= 1)
#pragma unroll
        for (int e = 0; e < 8; ++e) p[e] += __shfl_down(p[e], off);
      if (l == 0) {
        float m = p[0];
#pragma unroll
        for (int e = 1; e < 8; ++e) m = fmaxf(m, p[e]);
        float pr[8], s = 0.f;
#pragma unroll
        for (int e = 0; e < 8; ++e) { pr[e] = expf(p[e] - m); s += pr[e]; }
        float inv = 1.f / s;
#pragma unroll
        for (int e = 0; e < 8; ++e) { pr[e] *= inv; paux[e] += pr[e]; }
        int i1 = 0;
#pragma unroll
        for (int e = 1; e < 8; ++e) if (pr[e] > pr[i1]) i1 = e;
        int i2 = (i1 == 0) ? 1 : 0;
#pragma unroll
        for (int e = 0; e < 8; ++e) if (e != i1 && pr[e] > pr[i2]) i2 = e;
        float wsum = pr[i1] + pr[i2];
        gate[t * 8 + i1] = pr[i1] / wsum;
        gate[t * 8 + i2] = pr[i2] / wsum;
        int li = wv * 8 + tt;
        sei[li][0] = (unsigned char)i1;
        sei[li][1] = (unsigned char)i2;
      }
    }
    if (l == 0) {
#pragma unroll
      for (int e = 0; e < 8; ++e) sw[wv][e] = paux[e];
    }
    __syncthreads();
    if (threadIdx.x < 8) {
      const int e = threadIdx.x;
      auxpart[gid * 8 + e] = sw[0][e] + sw[1][e] + sw[2][e] + sw[3][e];
      int cnt = 0;
#pragma unroll 1
      for (int i = 0; i < 32; ++i) {
        if (sei[i][0] == e) spos[i][0] = (unsigned char)cnt++;
        if (sei[i][1] == e) spos[i][1] = (unsigned char)cnt++;
      }
      if (cnt) sbase[e] = atomicAdd(&counts[e << 5], cnt);
    }
    __syncthreads();
    if (threadIdx.x < 64) {
      int i = threadIdx.x >> 1, k = threadIdx.x & 1;
      int e = sei[i][k];
      lists[e * NT + sbase[e] + spos[i][k]] = t0 + i;
    }
  } else {
    // ------------------- transpose -------------------
    const int flat = gid - 256;
    const int z = flat >> 9;          // 0..15
    const int bx = flat & 511;
    const float* in;
    bf16* out;
    int R, C;
    if (z < 8) { in = W1 + (size_t)z * DD * HH; out = W1T + (size_t)z * DD * HH; R = DD; C = HH; }
    else       { in = W2 + (size_t)(z - 8) * DD * HH; out = W2T + (size_t)(z - 8) * DD * HH; R = HH; C = DD; }
    const int ntx = C >> 6;
    const int r0 = (bx / ntx) << 7, c0 = (bx % ntx) << 6;
    const int t = threadIdx.x;
    const int lrr = t >> 4, lc4 = (t & 15) * 4;
#pragma unroll
    for (int i = 0; i < 8; ++i) {
      int r = i * 16 + lrr;
      float4 v = *reinterpret_cast<const float4*>(in + (size_t)(r0 + r) * C + c0 + lc4);
      tile[r][lc4] = v.x; tile[r][lc4 + 1] = v.y; tile[r][lc4 + 2] = v.z; tile[r][lc4 + 3] = v.w;
    }
    __syncthreads();
    const int oc = t >> 4, m = t & 15;
#pragma unroll
    for (int cc = 0; cc < 4; ++cc) {
      int c = cc * 16 + oc;
      bf16x8 v;
#pragma unroll
      for (int k = 0; k < 8; ++k) v[k] = (bf16)tile[m * 8 + k][c];
      *reinterpret_cast<bf16x8*>(out + (size_t)(c0 + c) * R + r0 + m * 8) = v;
    }
  }
}

// --------- aux loss + prefix offsets + tile-prefix (for GEMM2 XCD coloring) ---------
__global__ void k_finalize(const int* __restrict__ counts, int* __restrict__ offs,
                           const float* __restrict__ auxpart, float* __restrict__ aux_out) {
  __shared__ float sh[32][8];
  int e = threadIdx.x & 7, chunk = threadIdx.x >> 3;  // 256 threads
  float s = 0.f;
  for (int b = chunk * 8; b < chunk * 8 + 8; ++b) s += auxpart[b * 8 + e];  // 256 blocks
  sh[chunk][e] = s;
  __syncthreads();
  if (threadIdx.x < 8) {
    float tot = 0.f;
    for (int c = 0; c < 32; ++c) tot += sh[c][threadIdx.x];
    float d = tot * (1.f / 8192.f) - 0.125f;
    sh[0][threadIdx.x] = d * d;
  }
  __syncthreads();
  if (threadIdx.x == 0) {
    float loss = 0.f;
    for (int e2 = 0; e2 < 8; ++e2) loss += sh[0][e2];
    aux_out[0] = loss;
    int o = 0, t = 0;
    for (int e2 = 0; e2 < 8; ++e2) {
      int c = counts[e2 << 5];
      offs[e2] = o;       o += c;
      offs[16 + e2] = t;  t += (c + 127) >> 7;   // tile prefix (tcum)
    }
    offs[8] = o;
    offs[24] = t;   // T = total (e,mt) pairs
  }
}

// --- grouped expert GEMM (128x128, BK=64, LDS dbuf) — 512 threads / 8 waves ---
// R20 config (frozen): 8 waves/block (2M x 4N), 2 blocks/CU -> 16 waves/CU.
// R7 schedule: stage tile k+1 at top of iter k into buf^1, vmcnt(4) waits
// only tile k. Swizzle c^(r&7) both sides. tanh-approx GELU.
// GEMM1 (!COLORED): 2-D n-fast grid (aggregate-L2 B sharing).
// GEMM2 (COLORED): 1-D XCD-colored grid (pair's A-tile pinned to one XCD L2).
#define BAR() do { asm volatile("" ::: "memory"); \
                   __builtin_amdgcn_s_barrier(); \
                   asm volatile("" ::: "memory"); } while (0)

template <int KTOT, int NTOT, bool IS_G1, bool COLORED>
__global__ __launch_bounds__(512, 4) void k_moe_gemm(
    const bf16* __restrict__ A, const bf16* __restrict__ Bw,
    bf16* __restrict__ Hout, float* __restrict__ Yout,
    const int* __restrict__ lists, const int* __restrict__ counts,
    const int* __restrict__ offs, const float* __restrict__ gate) {
  const int NX = NTOT / 128;
  int e, m0, n0;
  if (COLORED) {
    const int d = blockIdx.x;
    const int* tcum = offs + 16;
    const int T = tcum[8];
    const int p = ((d >> 3) / NX) * 8 + (d & 7);
    if (p >= T) return;
    e = 0;
    while (e < 7 && tcum[e + 1] <= p) ++e;
    m0 = (p - tcum[e]) * 128;
    n0 = ((d >> 3) % NX) * 128;
  } else {
    e = blockIdx.z;
    m0 = blockIdx.y * 128;
    n0 = blockIdx.x * 128;
  }
  const int count = counts[e << 5];
  if (m0 >= count) return;
  const int tid = threadIdx.x;
  const int w = tid >> 6, l = tid & 63;

  __shared__ __align__(16) char lds[65536];  // buf b at b*32768: A [0,16K), B [16K,32K)

  const int hoff = offs[e];
  const int srow = tid >> 3;               // 0..63
  const int schunk = ((tid & 7) ^ (srow & 7)) << 3;  // elems (pre-swizzled)
  const bf16* aptr[2];
  const bf16* bptr[2];
#pragma unroll
  for (int i = 0; i < 2; ++i) {
    int r = i * 64 + srow;
    int mrow = m0 + r; if (mrow > count - 1) mrow = count - 1;
    size_t arow = IS_G1 ? (size_t)lists[e * NT + mrow] : (size_t)(hoff + mrow);
    aptr[i] = A + arow * KTOT + schunk;
    bptr[i] = Bw + (size_t)e * NTOT * KTOT + (size_t)(n0 + r) * KTOT + schunk;
  }
  f32x4 acc[4][2];
#pragma unroll
  for (int mi = 0; mi < 4; ++mi)
#pragma unroll
    for (int ni = 0; ni < 2; ++ni) acc[mi][ni] = (f32x4){0.f, 0.f, 0.f, 0.f};

  // stage k-tile 0 -> buf0
#pragma unroll
  for (int i = 0; i < 2; ++i) gload_lds16(aptr[i], &lds[i * 8192 + w * 1024]);
#pragma unroll
  for (int i = 0; i < 2; ++i) gload_lds16(bptr[i], &lds[16384 + i * 8192 + w * 1024]);

  const int wm = w >> 2, wn = w & 3;       // 2M x 4N wave decomp
  const int lr = l & 15, lk = l >> 4;
  const int cb = (lk * 16) ^ ((l & 7) << 4);  // swizzled byte col
  const int abase = (wm * 64 + lr) * 128 + cb;
  const int bbase = 16384 + (wn * 32 + lr) * 128 + cb;

  const int NKT = KTOT / 64;
#pragma unroll 1
  for (int kt = 0; kt < NKT; ++kt) {
    const int cur = (kt & 1) * 32768;
    if (kt + 1 < NKT) {
      const int nxt = cur ^ 32768;
      const size_t ko = (size_t)(kt + 1) * 64;
#pragma unroll
      for (int i = 0; i < 2; ++i)
        gload_lds16(aptr[i] + ko, &lds[nxt + i * 8192 + w * 1024]);
#pragma unroll
      for (int i = 0; i < 2; ++i)
        gload_lds16(bptr[i] + ko, &lds[nxt + 16384 + i * 8192 + w * 1024]);
      asm volatile("s_waitcnt vmcnt(4)" ::: "memory");  // tile kt landed; kt+1 in flight
    } else {
      asm volatile("s_waitcnt vmcnt(0)" ::: "memory");
    }
    BAR();
#pragma unroll
    for (int ks = 0; ks < 2; ++ks) {
      bf16x8 af[4], bfr[2];
#pragma unroll
      for (int mi = 0; mi < 4; ++mi)
        af[mi] = *reinterpret_cast<const bf16x8*>(&lds[cur + ((abase + mi * 2048) ^ (ks << 6))]);
#pragma unroll
      for (int ni = 0; ni < 2; ++ni)
        bfr[ni] = *reinterpret_cast<const bf16x8*>(&lds[cur + ((bbase + ni * 2048) ^ (ks << 6))]);
#pragma unroll
      for (int mi = 0; mi < 4; ++mi)
#pragma unroll
        for (int ni = 0; ni < 2; ++ni)
          acc[mi][ni] = __builtin_amdgcn_mfma_f32_16x16x32_bf16(
              af[mi], bfr[ni], acc[mi][ni], 0, 0, 0);
    }
    BAR();  // all waves done reading buf cur -> next iter may overwrite it
  }

  // epilogue: rows wm*64+mi*16+lk*4+j, cols n0+wn*32+ni*16+lr
#pragma unroll
  for (int mi = 0; mi < 4; ++mi) {
#pragma unroll
    for (int j = 0; j < 4; ++j) {
      int row = wm * 64 + mi * 16 + lk * 4 + j;
      int m = m0 + row;
      if (m < count) {
        if (IS_G1) {
          size_t base = (size_t)(hoff + m) * NTOT + n0 + wn * 32 + lr;
#pragma unroll
          for (int ni = 0; ni < 2; ++ni) {
            float v = acc[mi][ni][j];
            float u = v + 0.044715f * v * v * v;
            float g = v / (1.f + __expf(-1.5957691216057308f * u));
            Hout[base + ni * 16] = (bf16)g;
          }
        } else {
          int tok = lists[e * NT + m];
          float wg = gate[tok * 8 + e];
          size_t base = (size_t)tok * 1024 + n0 + wn * 32 + lr;
#pragma unroll
          for (int ni = 0; ni < 2; ++ni)
            unsafeAtomicAdd(&Yout[base + ni * 16], wg * acc[mi][ni][j]);
        }
      }
    }
  }
}

extern "C" void kernel_launch(void* const* d_in, const int* in_sizes, int n_in,
                              void* d_out, int out_size, void* d_ws, size_t ws_size,
                              hipStream_t stream) {
  const float* x = (const float*)d_in[0];
  const float* Wr = (const float*)d_in[1];
  const float* W1 = (const float*)d_in[2];
  const float* W2 = (const float*)d_in[3];
  float* out = (float*)d_out;

  char* ws = (char*)d_ws;
  size_t off = 0;
  bf16* Xb = (bf16*)(ws + off);  off += (size_t)NT * DD * 2;        // 16.8 MB
  bf16* W1T = (bf16*)(ws + off); off += (size_t)NE * DD * HH * 2;   // 67 MB
  bf16* W2T = (bf16*)(ws + off); off += (size_t)NE * DD * HH * 2;   // 67 MB
  bf16* Hb = (bf16*)(ws + off);  off += (size_t)NT * 2 * HH * 2;    // 134 MB (16384 rows)
  float* gate = (float*)(ws + off); off += (size_t)NT * 8 * 4;
  int* lists = (int*)(ws + off);    off += (size_t)NE * NT * 4;
  int* counts = (int*)(ws + off);   off += 1024;  // padded: counts[e<<5]
  int* offs = (int*)(ws + off);     off += 128;   // [0..8] row offs, [16..24] tile prefix
  float* auxpart = (float*)(ws + off); off += (size_t)256 * 8 * 4;

  hipMemsetAsync(d_out, 0, (size_t)out_size * 4, stream);
  hipMemsetAsync(counts, 0, 1024, stream);

  k_pre<<<256 + 16 * 512, 256, 0, stream>>>(
      x, Wr, Xb, gate, lists, counts, auxpart, W1, W2, W1T, W2T);
  k_finalize<<<1, 256, 0, stream>>>(counts, offs, auxpart, out + (size_t)NT * DD);
  k_moe_gemm<DD, HH, true, false><<<dim3(HH / 128, 64, NE), 512, 0, stream>>>(
      Xb, W1T, Hb, nullptr, lists, counts, offs, gate);
  k_moe_gemm<HH, DD, false, true><<<TMAX * (DD / 128), 512, 0, stream>>>(
      Hb, W2T, nullptr, out, lists, counts, offs, gate);
}